// Round 5
// baseline (575.597 us; speedup 1.0000x reference)
//
#include <hip/hip_runtime.h>
#include <hip/hip_bf16.h>
#include <stdint.h>

// Problem constants (from reference)
#define S_  32
#define P_  48
#define T_  8
#define E_  64
#define H_  64
#define D1_ 512
#define D2_ 1024
#define B_  (S_*P_)        // 1536
#define M_  (S_*P_*P_)     // 73728 rows of the big GEMMs
#define K1_ 576            // T*E + H
#define KE_ 512            // T*E

typedef __attribute__((ext_vector_type(8))) short  short8;
typedef __attribute__((ext_vector_type(8))) __bf16 bf16x8;
typedef __attribute__((ext_vector_type(4))) float  f32x4;
typedef __attribute__((ext_vector_type(8))) float  f32x8;

// fp32 -> bf16 (round to nearest even), bit carrier = short
__device__ inline short f2bf(float x) {
  union { float f; unsigned u; } v; v.f = x;
  unsigned r = v.u + 0x7FFFu + ((v.u >> 16) & 1u);
  return (short)(r >> 16);
}

// async global->LDS, 16 bytes per lane (wave-uniform LDS base + lane*16; the
// GLOBAL source address is per-lane -> T2 swizzle done by pre-swizzling source)
__device__ inline void async16(const void* g, void* l) {
  __builtin_amdgcn_global_load_lds(
      (const __attribute__((address_space(1))) void*)g,
      (__attribute__((address_space(3))) void*)l, 16, 0, 0);
}

__device__ inline f32x4 mfma16(short8 a, short8 b, f32x4 c) {
  return __builtin_amdgcn_mfma_f32_16x16x32_bf16(
      __builtin_bit_cast(bf16x8, a), __builtin_bit_cast(bf16x8, b), c, 0, 0, 0);
}

// ---------------------------------------------------------------- K0: weights -> bf16
__global__ __launch_bounds__(256) void k_cvt_w(const float* __restrict__ W1,
                                               const float* __restrict__ W2,
                                               short* __restrict__ W1b,
                                               short* __restrict__ W2b) {
  int idx = blockIdx.x * 256 + threadIdx.x;
  if (idx < D1_ * K1_) W1b[idx] = f2bf(W1[idx]);
  int idx2 = idx - D1_ * K1_;
  if (idx2 >= 0 && idx2 < D2_ * D1_) W2b[idx2] = f2bf(W2[idx2]);
}

// ---------------------------------------------------------------- K0b: oW[p][n] = obs[p] @ Wse^T  (fp32)
__global__ __launch_bounds__(256) void k_oW(const float* __restrict__ traj,
                                            const float* __restrict__ Wse,
                                            float* __restrict__ oW) {
  int bid = blockIdx.x;                 // 1536*2 blocks
  int p = bid >> 1;
  int n = ((bid & 1) << 8) + threadIdx.x;
  float obs[16];
#pragma unroll
  for (int t = 0; t < T_; ++t) {
    obs[2*t]   = traj[(t*B_ + p)*2 + 0];
    obs[2*t+1] = traj[(t*B_ + p)*2 + 1];
  }
  float acc = 0.f;
#pragma unroll
  for (int k = 0; k < 16; ++k) acc += obs[k] * Wse[n*16 + k];
  oW[p*KE_ + n] = acc;
}

// ---------------------------------------------------------------- K1: build X (bf16)
// X[row=(s,i,j)][n<512]  = tw[s,rem,n&1,n>>6] * (oW[bj][n] - oW[bi][n] + bse[n])
// X[row][n>=512]         = h[bj][n-512]
__global__ __launch_bounds__(256) void k_build_x(const float* __restrict__ tw,
                                                 const float* __restrict__ h,
                                                 const float* __restrict__ bse,
                                                 const float* __restrict__ oW,
                                                 short* __restrict__ X) {
  int tid = threadIdx.x;
  int wid = tid >> 6, lane = tid & 63;
  int row = blockIdx.x * 4 + wid;
  int s   = row / (P_ * P_);
  int rem = row - s * (P_ * P_);
  int i   = rem / P_;
  int j   = rem - i * P_;
  int bi = s * P_ + i, bj = s * P_ + j;

  const float* twq = tw + (size_t)(s * (P_*P_) + rem) * 16;  // [2][8]
  int t = lane >> 3;                 // n>>6 for this lane's 8-elem chunk
  float w0 = twq[t];                 // c = 0 (even n)
  float w1 = twq[8 + t];             // c = 1 (odd n)

  int n0 = lane * 8;
  f32x8 vj = *(const f32x8*)&oW[(size_t)bj * KE_ + n0];
  f32x8 vi = *(const f32x8*)&oW[(size_t)bi * KE_ + n0];
  f32x8 vb = *(const f32x8*)&bse[n0];
  short8 o;
#pragma unroll
  for (int k = 0; k < 8; ++k) {
    float e = (vj[k] - vi[k] + vb[k]) * ((k & 1) ? w1 : w0);
    o[k] = f2bf(e);
  }
  *(short8*)&X[(size_t)row * K1_ + n0] = o;

  if (lane < 8) {                    // h tail: 64 elems = 8 lanes x short8
    f32x8 vh = *(const f32x8*)&h[(size_t)bj * H_ + lane * 8];
    short8 oh;
#pragma unroll
    for (int k = 0; k < 8; ++k) oh[k] = f2bf(vh[k]);
    *(short8*)&X[(size_t)row * K1_ + KE_ + lane * 8] = oh;
  }
}

// ---------------------------------------------------------------- K2: GEMM1 + relu
// X1 = relu(X[73728x576] @ W1b[512x576]^T + b1), bf16 out
// BM=128 BN=128 BK=64, 4 waves (2x2), wave tile 64x64, dbuf, 64 KB LDS
// -> 2 blocks/CU (drain of one block covered by the other's compute).
__global__ __launch_bounds__(256, 2) void k_gemm1(const short* __restrict__ X,
                                                  const short* __restrict__ W1b,
                                                  const float* __restrict__ b1,
                                                  short* __restrict__ X1) {
  __shared__ short Abuf[2][128 * 64];
  __shared__ short Bbuf[2][128 * 64];
  int tid = threadIdx.x;
  int wid = tid >> 6, lane = tid & 63;
  // T1: grid 2304 = 8 * 288; same-tm (4 tn) blocks land on same XCD adjacently
  int wgid = (blockIdx.x & 7) * 288 + (blockIdx.x >> 3);
  int tm = wgid >> 2, tn = wgid & 3;
  int brow = tm * 128, bcol = tn * 128;
  int wr = wid >> 1, wc = wid & 1;
  int lr = lane & 15, lhi = lane >> 4;
  int sx = lr & 7;                       // T2 read-side XOR (row&7 == lr&7)

  f32x4 acc[4][4];
#pragma unroll
  for (int m = 0; m < 4; ++m)
#pragma unroll
    for (int n = 0; n < 4; ++n) acc[m][n] = (f32x4){0.f, 0.f, 0.f, 0.f};

  auto stage = [&](int buf, int k0) {
#pragma unroll
    for (int it = 0; it < 4; ++it) {     // A: 128x64 = 1024 granules / 256 thr
      int fg = it * 256 + tid;
      int r = fg >> 3, gs = (fg & 7) ^ (r & 7);
      async16(&X  [(size_t)(brow + r) * K1_ + k0 + (gs << 3)], &Abuf[buf][fg * 8]);
    }
#pragma unroll
    for (int it = 0; it < 4; ++it) {     // B: 128x64
      int fg = it * 256 + tid;
      int r = fg >> 3, gs = (fg & 7) ^ (r & 7);
      async16(&W1b[(size_t)(bcol + r) * K1_ + k0 + (gs << 3)], &Bbuf[buf][fg * 8]);
    }
  };
  auto compute = [&](int buf) {
#pragma unroll
    for (int kk = 0; kk < 2; ++kk) {
      int gr = kk * 4 + lhi;
      short8 a[4], b[4];
#pragma unroll
      for (int m = 0; m < 4; ++m)
        a[m] = *(const short8*)&Abuf[buf][(wr*64 + m*16 + lr) * 64 + ((gr ^ sx) << 3)];
#pragma unroll
      for (int n = 0; n < 4; ++n)
        b[n] = *(const short8*)&Bbuf[buf][(wc*64 + n*16 + lr) * 64 + ((gr ^ sx) << 3)];
      __builtin_amdgcn_s_setprio(1);
#pragma unroll
      for (int m = 0; m < 4; ++m)
#pragma unroll
        for (int n = 0; n < 4; ++n)
          acc[m][n] = mfma16(a[m], b[n], acc[m][n]);
      __builtin_amdgcn_s_setprio(0);
    }
  };

  stage(0, 0);
  asm volatile("s_waitcnt vmcnt(0)" ::: "memory");
  __builtin_amdgcn_s_barrier();
  for (int t = 0; t < 9; ++t) {          // K1_/64 = 9 K-steps
    int cur = t & 1;
    if (t + 1 < 9) stage(cur ^ 1, (t + 1) * 64);   // issue BEFORE compute
    compute(cur);
    asm volatile("s_waitcnt vmcnt(0)" ::: "memory"); // drain AFTER compute
    __builtin_amdgcn_s_barrier();
  }

  // epilogue: bias + relu, bf16 store. C/D: row=(lane>>4)*4+q, col=lane&15
#pragma unroll
  for (int n = 0; n < 4; ++n) {
    int gcol = bcol + wc*64 + n*16 + lr;
    float bias = b1[gcol];
#pragma unroll
    for (int m = 0; m < 4; ++m) {
      int grow0 = brow + wr*64 + m*16 + lhi*4;
#pragma unroll
      for (int q = 0; q < 4; ++q) {
        float v = acc[m][n][q] + bias;
        v = v > 0.f ? v : 0.f;
        X1[(size_t)(grow0 + q) * D1_ + gcol] = f2bf(v);
      }
    }
  }
}

// ---------------------------------------------------------------- K3: GEMM2 + relu + max over j
// BM=192 (4 j-groups), BN=256, BK=32, 8 waves (2M x 4N), wave tile 96x64.
// dbuf LDS = 56 KB -> 2 blocks/CU. Swizzle: slot = g ^ (r&3) ^ ((r>>2)&3).
__global__ __launch_bounds__(512, 4) void k_gemm2(const short* __restrict__ X1,
                                                  const short* __restrict__ W2b,
                                                  const float* __restrict__ b2,
                                                  float* __restrict__ out) {
  __shared__ short Abuf[2][192 * 32];
  __shared__ short Bbuf[2][256 * 32];
  int tid = threadIdx.x;
  int wid = tid >> 6, lane = tid & 63;
  // T1: grid 1536 = 8 * 192
  int wgid = (blockIdx.x & 7) * 192 + (blockIdx.x >> 3);
  int tm = wgid >> 2, tn = wgid & 3;
  int brow = tm * 192, bcol = tn * 256;
  int wr = wid >> 2, wc = wid & 3;
  int lr = lane & 15, lhi = lane >> 4;
  int sx2 = (lr & 3) ^ ((lr >> 2) & 3);  // read-side XOR (row bits == lr bits)

  f32x4 acc[6][4];
#pragma unroll
  for (int m = 0; m < 6; ++m)
#pragma unroll
    for (int n = 0; n < 4; ++n) acc[m][n] = (f32x4){0.f, 0.f, 0.f, 0.f};

  // 1792 granules total: A = 768 (192 rows x 4), B = 1024 (256 rows x 4)
  auto ld1 = [&](int buf, int fg, int k0) {
    if (fg < 768) {
      int r = fg >> 2, g = fg & 3;
      int gs = g ^ (r & 3) ^ ((r >> 2) & 3);
      async16(&X1 [(size_t)(brow + r) * D1_ + k0 + (gs << 3)], &Abuf[buf][fg * 8]);
    } else {
      int fb = fg - 768;
      int r = fb >> 2, g = fb & 3;
      int gs = g ^ (r & 3) ^ ((r >> 2) & 3);
      async16(&W2b[(size_t)(bcol + r) * D1_ + k0 + (gs << 3)], &Bbuf[buf][fb * 8]);
    }
  };
  auto stage = [&](int buf, int k0) {
#pragma unroll
    for (int it = 0; it < 3; ++it) ld1(buf, it * 512 + tid, k0);
    if (tid < 256) ld1(buf, 1536 + tid, k0);
  };
  auto compute = [&](int buf) {
    int gr = lhi;                        // BK=32: one MFMA-K per step
    short8 a[6], b[4];
#pragma unroll
    for (int m = 0; m < 6; ++m)
      a[m] = *(const short8*)&Abuf[buf][(wr*96 + m*16 + lr) * 32 + ((gr ^ sx2) << 3)];
#pragma unroll
    for (int n = 0; n < 4; ++n)
      b[n] = *(const short8*)&Bbuf[buf][(wc*64 + n*16 + lr) * 32 + ((gr ^ sx2) << 3)];
    __builtin_amdgcn_s_setprio(1);
#pragma unroll
    for (int m = 0; m < 6; ++m)
#pragma unroll
      for (int n = 0; n < 4; ++n)
        acc[m][n] = mfma16(a[m], b[n], acc[m][n]);
    __builtin_amdgcn_s_setprio(0);
  };

  stage(0, 0);
  asm volatile("s_waitcnt vmcnt(0)" ::: "memory");
  __builtin_amdgcn_s_barrier();
  for (int t = 0; t < 16; ++t) {         // D1/32 = 16 K-steps
    int cur = t & 1;
    if (t + 1 < 16) stage(cur ^ 1, (t + 1) * 32);
    compute(cur);
    asm volatile("s_waitcnt vmcnt(0)" ::: "memory");
    __builtin_amdgcn_s_barrier();
  }

  // epilogue: wave rows = 2 j-groups (m 0..2 and 3..5); max + shfl reduce
  int gbase = tm * 4 + wr * 2;
#pragma unroll
  for (int n = 0; n < 4; ++n) {
    int gcol = bcol + wc*64 + n*16 + lr;
    float bias = b2[gcol];
    float r0 = 0.f, r1 = 0.f;            // relu floor == identity for max(relu)
#pragma unroll
    for (int m = 0; m < 3; ++m)
#pragma unroll
      for (int q = 0; q < 4; ++q) {
        float v0 = acc[m][n][q] + bias;
        float v1 = acc[m + 3][n][q] + bias;
        if (v0 > r0) r0 = v0;
        if (v1 > r1) r1 = v1;
      }
    r0 = fmaxf(r0, __shfl_xor(r0, 16));
    r0 = fmaxf(r0, __shfl_xor(r0, 32));
    r1 = fmaxf(r1, __shfl_xor(r1, 16));
    r1 = fmaxf(r1, __shfl_xor(r1, 32));
    if (lhi == 0) {
      out[(size_t)gbase       * D2_ + gcol] = r0;
      out[(size_t)(gbase + 1) * D2_ + gcol] = r1;
    }
  }
}

// ----------------------------------------------------------------
extern "C" void kernel_launch(void* const* d_in, const int* in_sizes, int n_in,
                              void* d_out, int out_size, void* d_ws, size_t ws_size,
                              hipStream_t stream) {
  const float* h_states = (const float*)d_in[0];
  const float* traj = (const float*)d_in[3];
  const float* tw   = (const float*)d_in[4];
  const float* Wse  = (const float*)d_in[6];
  const float* bse  = (const float*)d_in[7];
  const float* W1   = (const float*)d_in[8];
  const float* b1   = (const float*)d_in[9];
  const float* W2   = (const float*)d_in[10];
  const float* b2   = (const float*)d_in[11];
  float* out = (float*)d_out;

  char* ws = (char*)d_ws;
  const size_t X_BYTES   = (size_t)M_ * K1_ * 2;   // 84,934,656
  const size_t X1_BYTES  = (size_t)M_ * D1_ * 2;   // 75,497,472
  const size_t W1B_BYTES = (size_t)D1_ * K1_ * 2;  //    589,824
  short* X   = (short*)ws;
  short* X1  = (short*)(ws + X_BYTES);
  short* W1b = (short*)(ws + X_BYTES + X1_BYTES);
  short* W2b = (short*)(ws + X_BYTES + X1_BYTES + W1B_BYTES);
  // oW (3 MB fp32) aliases head of X1: consumed by k_build_x before k_gemm1
  float* oW  = (float*)(ws + X_BYTES);

  k_cvt_w  <<<(D1_*K1_ + D2_*D1_ + 255) / 256, 256, 0, stream>>>(W1, W2, W1b, W2b);
  k_oW     <<<B_ * 2, 256, 0, stream>>>(traj, Wse, oW);
  k_build_x<<<M_ / 4, 256, 0, stream>>>(tw, h_states, bse, oW, X);
  k_gemm1  <<<(M_ / 128) * (D1_ / 128), 256, 0, stream>>>(X, W1b, b1, X1);
  k_gemm2  <<<(M_ / 192) * (D2_ / 256), 512, 0, stream>>>(X1, W2b, b2, out);
}

// Round 6
// 261.438 us; speedup vs baseline: 2.2017x; 2.2017x over previous
//
#include <hip/hip_runtime.h>
#include <hip/hip_bf16.h>
#include <stdint.h>

// Problem constants (from reference)
#define S_  32
#define P_  48
#define T_  8
#define E_  64
#define H_  64
#define D1_ 512
#define D2_ 1024
#define B_  (S_*P_)        // 1536
#define M_  (S_*P_*P_)     // 73728 rows of the big GEMMs
#define K1_ 576            // T*E + H
#define KE_ 512            // T*E

typedef __attribute__((ext_vector_type(8))) short  short8;
typedef __attribute__((ext_vector_type(8))) __bf16 bf16x8;
typedef __attribute__((ext_vector_type(4))) float  f32x4;
typedef __attribute__((ext_vector_type(8))) float  f32x8;

// fp32 -> bf16 (round to nearest even), bit carrier = short
__device__ inline short f2bf(float x) {
  union { float f; unsigned u; } v; v.f = x;
  unsigned r = v.u + 0x7FFFu + ((v.u >> 16) & 1u);
  return (short)(r >> 16);
}

// async global->LDS, 16 bytes per lane (wave-uniform LDS base + lane*16; the
// GLOBAL source address is per-lane -> T2 swizzle done by pre-swizzling source)
__device__ inline void async16(const void* g, void* l) {
  __builtin_amdgcn_global_load_lds(
      (const __attribute__((address_space(1))) void*)g,
      (__attribute__((address_space(3))) void*)l, 16, 0, 0);
}

__device__ inline f32x4 mfma16(short8 a, short8 b, f32x4 c) {
  return __builtin_amdgcn_mfma_f32_16x16x32_bf16(
      __builtin_bit_cast(bf16x8, a), __builtin_bit_cast(bf16x8, b), c, 0, 0, 0);
}

// ---------------------------------------------------------------- K0: weights -> bf16
__global__ __launch_bounds__(256) void k_cvt_w(const float* __restrict__ W1,
                                               const float* __restrict__ W2,
                                               short* __restrict__ W1b,
                                               short* __restrict__ W2b) {
  int idx = blockIdx.x * 256 + threadIdx.x;
  if (idx < D1_ * K1_) W1b[idx] = f2bf(W1[idx]);
  int idx2 = idx - D1_ * K1_;
  if (idx2 >= 0 && idx2 < D2_ * D1_) W2b[idx2] = f2bf(W2[idx2]);
}

// ---------------------------------------------------------------- K0b: oW[p][n] = obs[p] @ Wse^T  (fp32)
__global__ __launch_bounds__(256) void k_oW(const float* __restrict__ traj,
                                            const float* __restrict__ Wse,
                                            float* __restrict__ oW) {
  int bid = blockIdx.x;                 // 1536*2 blocks
  int p = bid >> 1;
  int n = ((bid & 1) << 8) + threadIdx.x;
  float obs[16];
#pragma unroll
  for (int t = 0; t < T_; ++t) {
    obs[2*t]   = traj[(t*B_ + p)*2 + 0];
    obs[2*t+1] = traj[(t*B_ + p)*2 + 1];
  }
  float acc = 0.f;
#pragma unroll
  for (int k = 0; k < 16; ++k) acc += obs[k] * Wse[n*16 + k];
  oW[p*KE_ + n] = acc;
}

// ---------------------------------------------------------------- K1: build X (bf16)
// X[row=(s,i,j)][n<512]  = tw[s,rem,n&1,n>>6] * (oW[bj][n] - oW[bi][n] + bse[n])
// X[row][n>=512]         = h[bj][n-512]
__global__ __launch_bounds__(256) void k_build_x(const float* __restrict__ tw,
                                                 const float* __restrict__ h,
                                                 const float* __restrict__ bse,
                                                 const float* __restrict__ oW,
                                                 short* __restrict__ X) {
  int tid = threadIdx.x;
  int wid = tid >> 6, lane = tid & 63;
  int row = blockIdx.x * 4 + wid;
  int s   = row / (P_ * P_);
  int rem = row - s * (P_ * P_);
  int i   = rem / P_;
  int j   = rem - i * P_;
  int bi = s * P_ + i, bj = s * P_ + j;

  const float* twq = tw + (size_t)(s * (P_*P_) + rem) * 16;  // [2][8]
  int t = lane >> 3;                 // n>>6 for this lane's 8-elem chunk
  float w0 = twq[t];                 // c = 0 (even n)
  float w1 = twq[8 + t];             // c = 1 (odd n)

  int n0 = lane * 8;
  f32x8 vj = *(const f32x8*)&oW[(size_t)bj * KE_ + n0];
  f32x8 vi = *(const f32x8*)&oW[(size_t)bi * KE_ + n0];
  f32x8 vb = *(const f32x8*)&bse[n0];
  short8 o;
#pragma unroll
  for (int k = 0; k < 8; ++k) {
    float e = (vj[k] - vi[k] + vb[k]) * ((k & 1) ? w1 : w0);
    o[k] = f2bf(e);
  }
  *(short8*)&X[(size_t)row * K1_ + n0] = o;

  if (lane < 8) {                    // h tail: 64 elems = 8 lanes x short8
    f32x8 vh = *(const f32x8*)&h[(size_t)bj * H_ + lane * 8];
    short8 oh;
#pragma unroll
    for (int k = 0; k < 8; ++k) oh[k] = f2bf(vh[k]);
    *(short8*)&X[(size_t)row * K1_ + KE_ + lane * 8] = oh;
  }
}

// ---------------------------------------------------------------- K2: GEMM1 + relu
// X1 = relu(X[73728x576] @ W1b[512x576]^T + b1), bf16 out
// BM=128 BN=128 BK=64, 4 waves (2x2), wave tile 64x64, dbuf, 64 KB LDS
// -> 2 blocks/CU (drain of one block covered by the other's compute).
__global__ __launch_bounds__(256, 2) void k_gemm1(const short* __restrict__ X,
                                                  const short* __restrict__ W1b,
                                                  const float* __restrict__ b1,
                                                  short* __restrict__ X1) {
  __shared__ short Abuf[2][128 * 64];
  __shared__ short Bbuf[2][128 * 64];
  int tid = threadIdx.x;
  int wid = tid >> 6, lane = tid & 63;
  // T1: grid 2304 = 8 * 288; same-tm (4 tn) blocks land on same XCD adjacently
  int wgid = (blockIdx.x & 7) * 288 + (blockIdx.x >> 3);
  int tm = wgid >> 2, tn = wgid & 3;
  int brow = tm * 128, bcol = tn * 128;
  int wr = wid >> 1, wc = wid & 1;
  int lr = lane & 15, lhi = lane >> 4;
  int sx = lr & 7;                       // T2 read-side XOR (row&7 == lr&7)

  f32x4 acc[4][4];
#pragma unroll
  for (int m = 0; m < 4; ++m)
#pragma unroll
    for (int n = 0; n < 4; ++n) acc[m][n] = (f32x4){0.f, 0.f, 0.f, 0.f};

  auto stage = [&](int buf, int k0) {
#pragma unroll
    for (int it = 0; it < 4; ++it) {     // A: 128x64 = 1024 granules / 256 thr
      int fg = it * 256 + tid;
      int r = fg >> 3, gs = (fg & 7) ^ (r & 7);
      async16(&X  [(size_t)(brow + r) * K1_ + k0 + (gs << 3)], &Abuf[buf][fg * 8]);
    }
#pragma unroll
    for (int it = 0; it < 4; ++it) {     // B: 128x64
      int fg = it * 256 + tid;
      int r = fg >> 3, gs = (fg & 7) ^ (r & 7);
      async16(&W1b[(size_t)(bcol + r) * K1_ + k0 + (gs << 3)], &Bbuf[buf][fg * 8]);
    }
  };
  auto compute = [&](int buf) {
#pragma unroll
    for (int kk = 0; kk < 2; ++kk) {
      int gr = kk * 4 + lhi;
      short8 a[4], b[4];
#pragma unroll
      for (int m = 0; m < 4; ++m)
        a[m] = *(const short8*)&Abuf[buf][(wr*64 + m*16 + lr) * 64 + ((gr ^ sx) << 3)];
#pragma unroll
      for (int n = 0; n < 4; ++n)
        b[n] = *(const short8*)&Bbuf[buf][(wc*64 + n*16 + lr) * 64 + ((gr ^ sx) << 3)];
      __builtin_amdgcn_s_setprio(1);
#pragma unroll
      for (int m = 0; m < 4; ++m)
#pragma unroll
        for (int n = 0; n < 4; ++n)
          acc[m][n] = mfma16(a[m], b[n], acc[m][n]);
      __builtin_amdgcn_s_setprio(0);
    }
  };

  stage(0, 0);
  asm volatile("s_waitcnt vmcnt(0)" ::: "memory");
  __builtin_amdgcn_s_barrier();
  for (int t = 0; t < 9; ++t) {          // K1_/64 = 9 K-steps
    int cur = t & 1;
    if (t + 1 < 9) stage(cur ^ 1, (t + 1) * 64);   // issue BEFORE compute
    compute(cur);
    asm volatile("s_waitcnt vmcnt(0)" ::: "memory"); // drain AFTER compute
    __builtin_amdgcn_s_barrier();
  }

  // epilogue: bias + relu, bf16 store. C/D: row=(lane>>4)*4+q, col=lane&15
#pragma unroll
  for (int n = 0; n < 4; ++n) {
    int gcol = bcol + wc*64 + n*16 + lr;
    float bias = b1[gcol];
#pragma unroll
    for (int m = 0; m < 4; ++m) {
      int grow0 = brow + wr*64 + m*16 + lhi*4;
#pragma unroll
      for (int q = 0; q < 4; ++q) {
        float v = acc[m][n][q] + bias;
        v = v > 0.f ? v : 0.f;
        X1[(size_t)(grow0 + q) * D1_ + gcol] = f2bf(v);
      }
    }
  }
}

// ---------------------------------------------------------------- K3: GEMM2 + relu + max over j
// BM=192 (4 j-groups), BN=256, BK=32, 8 waves (2M x 4N), wave tile 96x64.
// dbuf LDS = 56 KB -> 2 blocks/CU (needs VGPR<=128: launch_bounds(512,2) caps
// at 256, compiler lands ~100 like R4 -- do NOT use min-waves=4, it spills).
// 64B rows: bank = 16*(r&1) + 4*slot; s(r) = ((r>>1)&3)^((r>>3)&1) gives
// uniform 2-way (= free, m136) across 16-lane quarter-waves.
__global__ __launch_bounds__(512, 2) void k_gemm2(const short* __restrict__ X1,
                                                  const short* __restrict__ W2b,
                                                  const float* __restrict__ b2,
                                                  float* __restrict__ out) {
  __shared__ short Abuf[2][192 * 32];
  __shared__ short Bbuf[2][256 * 32];
  int tid = threadIdx.x;
  int wid = tid >> 6, lane = tid & 63;
  // T1: grid 1536 = 8 * 192
  int wgid = (blockIdx.x & 7) * 192 + (blockIdx.x >> 3);
  int tm = wgid >> 2, tn = wgid & 3;
  int brow = tm * 192, bcol = tn * 256;
  int wr = wid >> 2, wc = wid & 3;
  int lr = lane & 15, lhi = lane >> 4;
  int sxr = ((lr >> 1) & 3) ^ ((lr >> 3) & 1);  // s(row) for row = base16k + lr

  f32x4 acc[6][4];
#pragma unroll
  for (int m = 0; m < 6; ++m)
#pragma unroll
    for (int n = 0; n < 4; ++n) acc[m][n] = (f32x4){0.f, 0.f, 0.f, 0.f};

  // 1792 granules total: A = 768 (192 rows x 4), B = 1024 (256 rows x 4)
  auto ld1 = [&](int buf, int fg, int k0) {
    if (fg < 768) {
      int r = fg >> 2, g = fg & 3;
      int gs = g ^ ((r >> 1) & 3) ^ ((r >> 3) & 1);
      async16(&X1 [(size_t)(brow + r) * D1_ + k0 + (gs << 3)], &Abuf[buf][fg * 8]);
    } else {
      int fb = fg - 768;
      int r = fb >> 2, g = fb & 3;
      int gs = g ^ ((r >> 1) & 3) ^ ((r >> 3) & 1);
      async16(&W2b[(size_t)(bcol + r) * D1_ + k0 + (gs << 3)], &Bbuf[buf][fb * 8]);
    }
  };
  auto stage = [&](int buf, int k0) {
#pragma unroll
    for (int it = 0; it < 3; ++it) ld1(buf, it * 512 + tid, k0);
    if (tid < 256) ld1(buf, 1536 + tid, k0);
  };
  auto compute = [&](int buf) {
    int gr = lhi;                        // BK=32: one MFMA-K per step
    short8 a[6], b[4];
#pragma unroll
    for (int m = 0; m < 6; ++m)
      a[m] = *(const short8*)&Abuf[buf][(wr*96 + m*16 + lr) * 32 + ((gr ^ sxr) << 3)];
#pragma unroll
    for (int n = 0; n < 4; ++n)
      b[n] = *(const short8*)&Bbuf[buf][(wc*64 + n*16 + lr) * 32 + ((gr ^ sxr) << 3)];
    __builtin_amdgcn_s_setprio(1);
#pragma unroll
    for (int m = 0; m < 6; ++m)
#pragma unroll
      for (int n = 0; n < 4; ++n)
        acc[m][n] = mfma16(a[m], b[n], acc[m][n]);
    __builtin_amdgcn_s_setprio(0);
  };

  stage(0, 0);
  asm volatile("s_waitcnt vmcnt(0)" ::: "memory");
  __builtin_amdgcn_s_barrier();
  for (int t = 0; t < 16; ++t) {         // D1/32 = 16 K-steps
    int cur = t & 1;
    if (t + 1 < 16) stage(cur ^ 1, (t + 1) * 32);
    compute(cur);
    asm volatile("s_waitcnt vmcnt(0)" ::: "memory");
    __builtin_amdgcn_s_barrier();
  }

  // epilogue: wave rows = 2 j-groups (m 0..2 and 3..5); max + shfl reduce
  int gbase = tm * 4 + wr * 2;
#pragma unroll
  for (int n = 0; n < 4; ++n) {
    int gcol = bcol + wc*64 + n*16 + lr;
    float bias = b2[gcol];
    float r0 = 0.f, r1 = 0.f;            // relu floor == identity for max(relu)
#pragma unroll
    for (int m = 0; m < 3; ++m)
#pragma unroll
      for (int q = 0; q < 4; ++q) {
        float v0 = acc[m][n][q] + bias;
        float v1 = acc[m + 3][n][q] + bias;
        if (v0 > r0) r0 = v0;
        if (v1 > r1) r1 = v1;
      }
    r0 = fmaxf(r0, __shfl_xor(r0, 16));
    r0 = fmaxf(r0, __shfl_xor(r0, 32));
    r1 = fmaxf(r1, __shfl_xor(r1, 16));
    r1 = fmaxf(r1, __shfl_xor(r1, 32));
    if (lhi == 0) {
      out[(size_t)gbase       * D2_ + gcol] = r0;
      out[(size_t)(gbase + 1) * D2_ + gcol] = r1;
    }
  }
}

// ----------------------------------------------------------------
extern "C" void kernel_launch(void* const* d_in, const int* in_sizes, int n_in,
                              void* d_out, int out_size, void* d_ws, size_t ws_size,
                              hipStream_t stream) {
  const float* h_states = (const float*)d_in[0];
  const float* traj = (const float*)d_in[3];
  const float* tw   = (const float*)d_in[4];
  const float* Wse  = (const float*)d_in[6];
  const float* bse  = (const float*)d_in[7];
  const float* W1   = (const float*)d_in[8];
  const float* b1   = (const float*)d_in[9];
  const float* W2   = (const float*)d_in[10];
  const float* b2   = (const float*)d_in[11];
  float* out = (float*)d_out;

  char* ws = (char*)d_ws;
  const size_t X_BYTES   = (size_t)M_ * K1_ * 2;   // 84,934,656
  const size_t X1_BYTES  = (size_t)M_ * D1_ * 2;   // 75,497,472
  const size_t W1B_BYTES = (size_t)D1_ * K1_ * 2;  //    589,824
  short* X   = (short*)ws;
  short* X1  = (short*)(ws + X_BYTES);
  short* W1b = (short*)(ws + X_BYTES + X1_BYTES);
  short* W2b = (short*)(ws + X_BYTES + X1_BYTES + W1B_BYTES);
  // oW (3 MB fp32) aliases head of X1: consumed by k_build_x before k_gemm1
  float* oW  = (float*)(ws + X_BYTES);

  k_cvt_w  <<<(D1_*K1_ + D2_*D1_ + 255) / 256, 256, 0, stream>>>(W1, W2, W1b, W2b);
  k_oW     <<<B_ * 2, 256, 0, stream>>>(traj, Wse, oW);
  k_build_x<<<M_ / 4, 256, 0, stream>>>(tw, h_states, bse, oW, X);
  k_gemm1  <<<(M_ / 128) * (D1_ / 128), 256, 0, stream>>>(X, W1b, b1, X1);
  k_gemm2  <<<(M_ / 192) * (D2_ / 256), 512, 0, stream>>>(X1, W2b, b2, out);
}

// Round 7
// 258.365 us; speedup vs baseline: 2.2278x; 1.0119x over previous
//
#include <hip/hip_runtime.h>
#include <hip/hip_bf16.h>
#include <stdint.h>

// Problem constants (from reference)
#define S_  32
#define P_  48
#define T_  8
#define E_  64
#define H_  64
#define D1_ 512
#define D2_ 1024
#define B_  (S_*P_)        // 1536
#define M_  (S_*P_*P_)     // 73728 rows of the big GEMMs
#define K1_ 576            // T*E + H
#define KE_ 512            // T*E

typedef __attribute__((ext_vector_type(8))) short  short8;
typedef __attribute__((ext_vector_type(8))) __bf16 bf16x8;
typedef __attribute__((ext_vector_type(4))) float  f32x4;
typedef __attribute__((ext_vector_type(8))) float  f32x8;

// fp32 -> bf16 (round to nearest even), bit carrier = short
__device__ inline short f2bf(float x) {
  union { float f; unsigned u; } v; v.f = x;
  unsigned r = v.u + 0x7FFFu + ((v.u >> 16) & 1u);
  return (short)(r >> 16);
}

// async global->LDS, 16 bytes per lane (wave-uniform LDS base + lane*16; the
// GLOBAL source address is per-lane -> T2 swizzle done by pre-swizzling source)
__device__ inline void async16(const void* g, void* l) {
  __builtin_amdgcn_global_load_lds(
      (const __attribute__((address_space(1))) void*)g,
      (__attribute__((address_space(3))) void*)l, 16, 0, 0);
}

__device__ inline f32x4 mfma16(short8 a, short8 b, f32x4 c) {
  return __builtin_amdgcn_mfma_f32_16x16x32_bf16(
      __builtin_bit_cast(bf16x8, a), __builtin_bit_cast(bf16x8, b), c, 0, 0, 0);
}

// ---------------------------------------------------------------- K0: weights -> bf16
__global__ __launch_bounds__(256) void k_cvt_w(const float* __restrict__ W1,
                                               const float* __restrict__ W2,
                                               short* __restrict__ W1b,
                                               short* __restrict__ W2b) {
  int idx = blockIdx.x * 256 + threadIdx.x;
  if (idx < D1_ * K1_) W1b[idx] = f2bf(W1[idx]);
  int idx2 = idx - D1_ * K1_;
  if (idx2 >= 0 && idx2 < D2_ * D1_) W2b[idx2] = f2bf(W2[idx2]);
}

// ---------------------------------------------------------------- K0b: oW[p][n] = obs[p] @ Wse^T  (fp32)
__global__ __launch_bounds__(256) void k_oW(const float* __restrict__ traj,
                                            const float* __restrict__ Wse,
                                            float* __restrict__ oW) {
  int bid = blockIdx.x;                 // 1536*2 blocks
  int p = bid >> 1;
  int n = ((bid & 1) << 8) + threadIdx.x;
  float obs[16];
#pragma unroll
  for (int t = 0; t < T_; ++t) {
    obs[2*t]   = traj[(t*B_ + p)*2 + 0];
    obs[2*t+1] = traj[(t*B_ + p)*2 + 1];
  }
  float acc = 0.f;
#pragma unroll
  for (int k = 0; k < 16; ++k) acc += obs[k] * Wse[n*16 + k];
  oW[p*KE_ + n] = acc;
}

// ---------------------------------------------------------------- K1: build X (bf16)
// X[row=(s,i,j)][n<512]  = tw[s,rem,n&1,n>>6] * (oW[bj][n] - oW[bi][n] + bse[n])
// X[row][n>=512]         = h[bj][n-512]
__global__ __launch_bounds__(256) void k_build_x(const float* __restrict__ tw,
                                                 const float* __restrict__ h,
                                                 const float* __restrict__ bse,
                                                 const float* __restrict__ oW,
                                                 short* __restrict__ X) {
  int tid = threadIdx.x;
  int wid = tid >> 6, lane = tid & 63;
  int row = blockIdx.x * 4 + wid;
  int s   = row / (P_ * P_);
  int rem = row - s * (P_ * P_);
  int i   = rem / P_;
  int j   = rem - i * P_;
  int bi = s * P_ + i, bj = s * P_ + j;

  const float* twq = tw + (size_t)(s * (P_*P_) + rem) * 16;  // [2][8]
  int t = lane >> 3;                 // n>>6 for this lane's 8-elem chunk
  float w0 = twq[t];                 // c = 0 (even n)
  float w1 = twq[8 + t];             // c = 1 (odd n)

  int n0 = lane * 8;
  f32x8 vj = *(const f32x8*)&oW[(size_t)bj * KE_ + n0];
  f32x8 vi = *(const f32x8*)&oW[(size_t)bi * KE_ + n0];
  f32x8 vb = *(const f32x8*)&bse[n0];
  short8 o;
#pragma unroll
  for (int k = 0; k < 8; ++k) {
    float e = (vj[k] - vi[k] + vb[k]) * ((k & 1) ? w1 : w0);
    o[k] = f2bf(e);
  }
  *(short8*)&X[(size_t)row * K1_ + n0] = o;

  if (lane < 8) {                    // h tail: 64 elems = 8 lanes x short8
    f32x8 vh = *(const f32x8*)&h[(size_t)bj * H_ + lane * 8];
    short8 oh;
#pragma unroll
    for (int k = 0; k < 8; ++k) oh[k] = f2bf(vh[k]);
    *(short8*)&X[(size_t)row * K1_ + KE_ + lane * 8] = oh;
  }
}

// ---------------------------------------------------------------- K2: GEMM1 + relu
// X1 = relu(X[73728x576] @ W1b[512x576]^T + b1), bf16 out
// BM=128 BN=256 BK=64, 8 waves (2M x 4N), wave tile 64x64.
// Counted-vmcnt pipeline: A dbuf (1 ahead), B tribuf (2 ahead);
// per K-step wait vmcnt(4) -> newest 4 loads (B(t+2)) stay in flight.
__global__ __launch_bounds__(512, 2) void k_gemm1(const short* __restrict__ X,
                                                  const short* __restrict__ W1b,
                                                  const float* __restrict__ b1,
                                                  short* __restrict__ X1) {
  __shared__ short Abuf[2][128 * 64];   //  32 KB
  __shared__ short Bbuf[3][256 * 64];   //  96 KB  (total 128 KB)
  int tid = threadIdx.x;
  int wid = tid >> 6, lane = tid & 63;
  // T1: grid 1152 = 8 * 144; consecutive wgid (same XCD) share A-panel
  int wgid = (blockIdx.x & 7) * 144 + (blockIdx.x >> 3);
  int tm = wgid >> 1, tn = wgid & 1;
  int brow = tm * 128, bcol = tn * 256;
  int wr = wid >> 2, wc = wid & 3;       // 2M x 4N
  int lr = lane & 15, lhi = lane >> 4;
  int sx = lr & 7;                       // T2 read-side XOR (row&7 == lr&7)

  f32x4 acc[4][4];
#pragma unroll
  for (int m = 0; m < 4; ++m)
#pragma unroll
    for (int n = 0; n < 4; ++n) acc[m][n] = (f32x4){0.f, 0.f, 0.f, 0.f};

  auto stageA = [&](int buf, int k0) {   // 1024 granules / 512 thr = 2
#pragma unroll
    for (int it = 0; it < 2; ++it) {
      int fg = it * 512 + tid;
      int r = fg >> 3, gs = (fg & 7) ^ (r & 7);
      async16(&X[(size_t)(brow + r) * K1_ + k0 + (gs << 3)], &Abuf[buf][fg * 8]);
    }
  };
  auto stageB = [&](int buf, int k0) {   // 2048 granules / 512 thr = 4
#pragma unroll
    for (int it = 0; it < 4; ++it) {
      int fg = it * 512 + tid;
      int r = fg >> 3, gs = (fg & 7) ^ (r & 7);
      async16(&W1b[(size_t)(bcol + r) * K1_ + k0 + (gs << 3)], &Bbuf[buf][fg * 8]);
    }
  };
  auto compute = [&](int bA, int bB) {
#pragma unroll
    for (int kk = 0; kk < 2; ++kk) {
      int gr = kk * 4 + lhi;
      short8 a[4], b[4];
#pragma unroll
      for (int m = 0; m < 4; ++m)
        a[m] = *(const short8*)&Abuf[bA][(wr*64 + m*16 + lr) * 64 + ((gr ^ sx) << 3)];
#pragma unroll
      for (int n = 0; n < 4; ++n)
        b[n] = *(const short8*)&Bbuf[bB][(wc*64 + n*16 + lr) * 64 + ((gr ^ sx) << 3)];
      __builtin_amdgcn_s_setprio(1);
#pragma unroll
      for (int m = 0; m < 4; ++m)
#pragma unroll
        for (int n = 0; n < 4; ++n)
          acc[m][n] = mfma16(a[m], b[n], acc[m][n]);
      __builtin_amdgcn_s_setprio(0);
    }
  };

  const int NT = 9;                      // K1_/64
  // prologue: A(0), B(0), B(1); wait so A(0),B(0) landed (B(1) in flight)
  stageA(0, 0); stageB(0, 0); stageB(1, 64);
  asm volatile("s_waitcnt vmcnt(4)" ::: "memory");
  __builtin_amdgcn_s_barrier();
#pragma unroll
  for (int t = 0; t < NT; ++t) {
    if (t + 1 < NT) stageA((t + 1) & 1, (t + 1) * 64);
    if (t + 2 < NT) stageB((t + 2) % 3, (t + 2) * 64);
    compute(t & 1, t % 3);
    if (t + 2 < NT)      { asm volatile("s_waitcnt vmcnt(4)" ::: "memory"); }
    else if (t + 1 < NT) { asm volatile("s_waitcnt vmcnt(0)" ::: "memory"); }
    if (t + 1 < NT) __builtin_amdgcn_s_barrier();
  }

  // epilogue: bias + relu, bf16 store. C/D: row=(lane>>4)*4+q, col=lane&15
#pragma unroll
  for (int n = 0; n < 4; ++n) {
    int gcol = bcol + wc*64 + n*16 + lr;
    float bias = b1[gcol];
#pragma unroll
    for (int m = 0; m < 4; ++m) {
      int grow0 = brow + wr*64 + m*16 + lhi*4;
#pragma unroll
      for (int q = 0; q < 4; ++q) {
        float v = acc[m][n][q] + bias;
        v = v > 0.f ? v : 0.f;
        X1[(size_t)(grow0 + q) * D1_ + gcol] = f2bf(v);
      }
    }
  }
}

// ---------------------------------------------------------------- K3: GEMM2 + relu + max over j
// BM=192 (4 j-groups), BN=256, BK=64, 8 waves (2M x 4N), wave tile 96x64.
// Same counted-vmcnt pipeline. LDS 144 KB (<= 160 KB HW). Epilogue: per-group
// max over 3 m-frags x 4 q + shfl_xor(16,32).
__global__ __launch_bounds__(512, 2) void k_gemm2(const short* __restrict__ X1,
                                                  const short* __restrict__ W2b,
                                                  const float* __restrict__ b2,
                                                  float* __restrict__ out) {
  __shared__ short Abuf[2][192 * 64];   //  48 KB
  __shared__ short Bbuf[3][256 * 64];   //  96 KB  (total 144 KB)
  int tid = threadIdx.x;
  int wid = tid >> 6, lane = tid & 63;
  // T1: grid 1536 = 8 * 192; 4 consecutive wgid (same XCD) share A-panel
  int wgid = (blockIdx.x & 7) * 192 + (blockIdx.x >> 3);
  int tm = wgid >> 2, tn = wgid & 3;
  int brow = tm * 192, bcol = tn * 256;
  int wr = wid >> 2, wc = wid & 3;
  int lr = lane & 15, lhi = lane >> 4;
  int sx = lr & 7;

  f32x4 acc[6][4];
#pragma unroll
  for (int m = 0; m < 6; ++m)
#pragma unroll
    for (int n = 0; n < 4; ++n) acc[m][n] = (f32x4){0.f, 0.f, 0.f, 0.f};

  auto stageA = [&](int buf, int k0) {   // 1536 granules / 512 thr = 3
#pragma unroll
    for (int it = 0; it < 3; ++it) {
      int fg = it * 512 + tid;
      int r = fg >> 3, gs = (fg & 7) ^ (r & 7);
      async16(&X1[(size_t)(brow + r) * D1_ + k0 + (gs << 3)], &Abuf[buf][fg * 8]);
    }
  };
  auto stageB = [&](int buf, int k0) {   // 2048 granules / 512 thr = 4
#pragma unroll
    for (int it = 0; it < 4; ++it) {
      int fg = it * 512 + tid;
      int r = fg >> 3, gs = (fg & 7) ^ (r & 7);
      async16(&W2b[(size_t)(bcol + r) * D1_ + k0 + (gs << 3)], &Bbuf[buf][fg * 8]);
    }
  };
  auto compute = [&](int bA, int bB) {
#pragma unroll
    for (int kk = 0; kk < 2; ++kk) {
      int gr = kk * 4 + lhi;
      short8 a[6], b[4];
#pragma unroll
      for (int m = 0; m < 6; ++m)
        a[m] = *(const short8*)&Abuf[bA][(wr*96 + m*16 + lr) * 64 + ((gr ^ sx) << 3)];
#pragma unroll
      for (int n = 0; n < 4; ++n)
        b[n] = *(const short8*)&Bbuf[bB][(wc*64 + n*16 + lr) * 64 + ((gr ^ sx) << 3)];
      __builtin_amdgcn_s_setprio(1);
#pragma unroll
      for (int m = 0; m < 6; ++m)
#pragma unroll
        for (int n = 0; n < 4; ++n)
          acc[m][n] = mfma16(a[m], b[n], acc[m][n]);
      __builtin_amdgcn_s_setprio(0);
    }
  };

  const int NT = 8;                      // D1_/64
  stageA(0, 0); stageB(0, 0); stageB(1, 64);
  asm volatile("s_waitcnt vmcnt(4)" ::: "memory");
  __builtin_amdgcn_s_barrier();
#pragma unroll
  for (int t = 0; t < NT; ++t) {
    if (t + 1 < NT) stageA((t + 1) & 1, (t + 1) * 64);
    if (t + 2 < NT) stageB((t + 2) % 3, (t + 2) * 64);
    compute(t & 1, t % 3);
    if (t + 2 < NT)      { asm volatile("s_waitcnt vmcnt(4)" ::: "memory"); }
    else if (t + 1 < NT) { asm volatile("s_waitcnt vmcnt(0)" ::: "memory"); }
    if (t + 1 < NT) __builtin_amdgcn_s_barrier();
  }

  // epilogue: wave rows = 2 j-groups (m 0..2 and 3..5); max + shfl reduce
  int gbase = tm * 4 + wr * 2;
#pragma unroll
  for (int n = 0; n < 4; ++n) {
    int gcol = bcol + wc*64 + n*16 + lr;
    float bias = b2[gcol];
    float r0 = 0.f, r1 = 0.f;            // relu floor == identity for max(relu)
#pragma unroll
    for (int m = 0; m < 3; ++m)
#pragma unroll
      for (int q = 0; q < 4; ++q) {
        float v0 = acc[m][n][q] + bias;
        float v1 = acc[m + 3][n][q] + bias;
        if (v0 > r0) r0 = v0;
        if (v1 > r1) r1 = v1;
      }
    r0 = fmaxf(r0, __shfl_xor(r0, 16));
    r0 = fmaxf(r0, __shfl_xor(r0, 32));
    r1 = fmaxf(r1, __shfl_xor(r1, 16));
    r1 = fmaxf(r1, __shfl_xor(r1, 32));
    if (lhi == 0) {
      out[(size_t)gbase       * D2_ + gcol] = r0;
      out[(size_t)(gbase + 1) * D2_ + gcol] = r1;
    }
  }
}

// ----------------------------------------------------------------
extern "C" void kernel_launch(void* const* d_in, const int* in_sizes, int n_in,
                              void* d_out, int out_size, void* d_ws, size_t ws_size,
                              hipStream_t stream) {
  const float* h_states = (const float*)d_in[0];
  const float* traj = (const float*)d_in[3];
  const float* tw   = (const float*)d_in[4];
  const float* Wse  = (const float*)d_in[6];
  const float* bse  = (const float*)d_in[7];
  const float* W1   = (const float*)d_in[8];
  const float* b1   = (const float*)d_in[9];
  const float* W2   = (const float*)d_in[10];
  const float* b2   = (const float*)d_in[11];
  float* out = (float*)d_out;

  char* ws = (char*)d_ws;
  const size_t X_BYTES   = (size_t)M_ * K1_ * 2;   // 84,934,656
  const size_t X1_BYTES  = (size_t)M_ * D1_ * 2;   // 75,497,472
  const size_t W1B_BYTES = (size_t)D1_ * K1_ * 2;  //    589,824
  short* X   = (short*)ws;
  short* X1  = (short*)(ws + X_BYTES);
  short* W1b = (short*)(ws + X_BYTES + X1_BYTES);
  short* W2b = (short*)(ws + X_BYTES + X1_BYTES + W1B_BYTES);
  // oW (3 MB fp32) aliases head of X1: consumed by k_build_x before k_gemm1
  float* oW  = (float*)(ws + X_BYTES);

  k_cvt_w  <<<(D1_*K1_ + D2_*D1_ + 255) / 256, 256, 0, stream>>>(W1, W2, W1b, W2b);
  k_oW     <<<B_ * 2, 256, 0, stream>>>(traj, Wse, oW);
  k_build_x<<<M_ / 4, 256, 0, stream>>>(tw, h_states, bse, oW, X);
  k_gemm1  <<<(M_ / 128) * (D1_ / 256), 512, 0, stream>>>(X, W1b, b1, X1);
  k_gemm2  <<<(M_ / 192) * (D2_ / 256), 512, 0, stream>>>(X1, W2b, b2, out);
}

// Round 8
// 248.079 us; speedup vs baseline: 2.3202x; 1.0415x over previous
//
#include <hip/hip_runtime.h>
#include <hip/hip_bf16.h>
#include <stdint.h>

// Problem constants (from reference)
#define S_  32
#define P_  48
#define T_  8
#define E_  64
#define H_  64
#define D1_ 512
#define D2_ 1024
#define B_  (S_*P_)        // 1536
#define M_  (S_*P_*P_)     // 73728 rows of the big GEMMs
#define K1_ 576            // T*E + H
#define KE_ 512            // T*E

typedef __attribute__((ext_vector_type(8))) short  short8;
typedef __attribute__((ext_vector_type(8))) __bf16 bf16x8;
typedef __attribute__((ext_vector_type(4))) float  f32x4;
typedef __attribute__((ext_vector_type(8))) float  f32x8;

// fp32 -> bf16 (round to nearest even), bit carrier = short
__device__ inline short f2bf(float x) {
  union { float f; unsigned u; } v; v.f = x;
  unsigned r = v.u + 0x7FFFu + ((v.u >> 16) & 1u);
  return (short)(r >> 16);
}

// async global->LDS, 16 bytes per lane (wave-uniform LDS base + lane*16; the
// GLOBAL source address is per-lane -> T2 swizzle done by pre-swizzling source)
__device__ inline void async16(const void* g, void* l) {
  __builtin_amdgcn_global_load_lds(
      (const __attribute__((address_space(1))) void*)g,
      (__attribute__((address_space(3))) void*)l, 16, 0, 0);
}

__device__ inline f32x4 mfma16(short8 a, short8 b, f32x4 c) {
  return __builtin_amdgcn_mfma_f32_16x16x32_bf16(
      __builtin_bit_cast(bf16x8, a), __builtin_bit_cast(bf16x8, b), c, 0, 0, 0);
}

#define LGKM0_FENCE() do { \
  asm volatile("s_waitcnt lgkmcnt(0)" ::: "memory"); \
  __builtin_amdgcn_sched_barrier(0); } while (0)

// ---------------------------------------------------------------- K0: weights -> bf16
__global__ __launch_bounds__(256) void k_cvt_w(const float* __restrict__ W1,
                                               const float* __restrict__ W2,
                                               short* __restrict__ W1b,
                                               short* __restrict__ W2b) {
  int idx = blockIdx.x * 256 + threadIdx.x;
  if (idx < D1_ * K1_) W1b[idx] = f2bf(W1[idx]);
  int idx2 = idx - D1_ * K1_;
  if (idx2 >= 0 && idx2 < D2_ * D1_) W2b[idx2] = f2bf(W2[idx2]);
}

// ---------------------------------------------------------------- K0b: oW[p][n] = obs[p] @ Wse^T  (fp32)
__global__ __launch_bounds__(256) void k_oW(const float* __restrict__ traj,
                                            const float* __restrict__ Wse,
                                            float* __restrict__ oW) {
  int bid = blockIdx.x;                 // 1536*2 blocks
  int p = bid >> 1;
  int n = ((bid & 1) << 8) + threadIdx.x;
  float obs[16];
#pragma unroll
  for (int t = 0; t < T_; ++t) {
    obs[2*t]   = traj[(t*B_ + p)*2 + 0];
    obs[2*t+1] = traj[(t*B_ + p)*2 + 1];
  }
  float acc = 0.f;
#pragma unroll
  for (int k = 0; k < 16; ++k) acc += obs[k] * Wse[n*16 + k];
  oW[p*KE_ + n] = acc;
}

// ---------------------------------------------------------------- K1: build X (bf16)
__global__ __launch_bounds__(256) void k_build_x(const float* __restrict__ tw,
                                                 const float* __restrict__ h,
                                                 const float* __restrict__ bse,
                                                 const float* __restrict__ oW,
                                                 short* __restrict__ X) {
  int tid = threadIdx.x;
  int wid = tid >> 6, lane = tid & 63;
  int row = blockIdx.x * 4 + wid;
  int s   = row / (P_ * P_);
  int rem = row - s * (P_ * P_);
  int i   = rem / P_;
  int j   = rem - i * P_;
  int bi = s * P_ + i, bj = s * P_ + j;

  const float* twq = tw + (size_t)(s * (P_*P_) + rem) * 16;  // [2][8]
  int t = lane >> 3;
  float w0 = twq[t];
  float w1 = twq[8 + t];

  int n0 = lane * 8;
  f32x8 vj = *(const f32x8*)&oW[(size_t)bj * KE_ + n0];
  f32x8 vi = *(const f32x8*)&oW[(size_t)bi * KE_ + n0];
  f32x8 vb = *(const f32x8*)&bse[n0];
  short8 o;
#pragma unroll
  for (int k = 0; k < 8; ++k) {
    float e = (vj[k] - vi[k] + vb[k]) * ((k & 1) ? w1 : w0);
    o[k] = f2bf(e);
  }
  *(short8*)&X[(size_t)row * K1_ + n0] = o;

  if (lane < 8) {
    f32x8 vh = *(const f32x8*)&h[(size_t)bj * H_ + lane * 8];
    short8 oh;
#pragma unroll
    for (int k = 0; k < 8; ++k) oh[k] = f2bf(vh[k]);
    *(short8*)&X[(size_t)row * K1_ + KE_ + lane * 8] = oh;
  }
}

// ---------------------------------------------------------------- K2: GEMM1 + relu
// X1 = relu(X[73728x576] @ W1b[512x576]^T + b1), bf16 out
// BM=128 BN=128 BK=64, 4 waves (2x2), wave 64x64, dbuf 64 KB -> 2 blocks/CU.
// Phase-split K-step: 2 phases (kk0/kk1), each {ds_read; stage; bar; lgkm0;
// setprio; 16 MFMA; setprio; bar}. End-of-tile vmcnt(0) covered by co-block.
__global__ __launch_bounds__(256, 2) void k_gemm1(const short* __restrict__ X,
                                                  const short* __restrict__ W1b,
                                                  const float* __restrict__ b1,
                                                  short* __restrict__ X1) {
  __shared__ short Abuf[2][128 * 64];
  __shared__ short Bbuf[2][128 * 64];
  int tid = threadIdx.x;
  int wid = tid >> 6, lane = tid & 63;
  // T1: grid 2304 = 8 * 288
  int wgid = (blockIdx.x & 7) * 288 + (blockIdx.x >> 3);
  int tm = wgid >> 2, tn = wgid & 3;
  int brow = tm * 128, bcol = tn * 128;
  int wr = wid >> 1, wc = wid & 1;
  int lr = lane & 15, lhi = lane >> 4;
  int sx = lr & 7;

  f32x4 acc[4][4];
#pragma unroll
  for (int m = 0; m < 4; ++m)
#pragma unroll
    for (int n = 0; n < 4; ++n) acc[m][n] = (f32x4){0.f, 0.f, 0.f, 0.f};

  auto stageA = [&](int buf, int k0) {
#pragma unroll
    for (int it = 0; it < 4; ++it) {
      int fg = it * 256 + tid;
      int r = fg >> 3, gs = (fg & 7) ^ (r & 7);
      async16(&X[(size_t)(brow + r) * K1_ + k0 + (gs << 3)], &Abuf[buf][fg * 8]);
    }
  };
  auto stageB = [&](int buf, int k0) {
#pragma unroll
    for (int it = 0; it < 4; ++it) {
      int fg = it * 256 + tid;
      int r = fg >> 3, gs = (fg & 7) ^ (r & 7);
      async16(&W1b[(size_t)(bcol + r) * K1_ + k0 + (gs << 3)], &Bbuf[buf][fg * 8]);
    }
  };
  auto dsA = [&](int buf, int kk, short8* a) {
    int gr = kk * 4 + lhi;
#pragma unroll
    for (int m = 0; m < 4; ++m)
      a[m] = *(const short8*)&Abuf[buf][(wr*64 + m*16 + lr) * 64 + ((gr ^ sx) << 3)];
  };
  auto dsB = [&](int buf, int kk, short8* b) {
    int gr = kk * 4 + lhi;
#pragma unroll
    for (int n = 0; n < 4; ++n)
      b[n] = *(const short8*)&Bbuf[buf][(wc*64 + n*16 + lr) * 64 + ((gr ^ sx) << 3)];
  };
  auto mf16 = [&](short8* a, short8* b) {
    __builtin_amdgcn_s_setprio(1);
#pragma unroll
    for (int m = 0; m < 4; ++m)
#pragma unroll
      for (int n = 0; n < 4; ++n)
        acc[m][n] = mfma16(a[m], b[n], acc[m][n]);
    __builtin_amdgcn_s_setprio(0);
  };

  const int NT = 9;                      // K1_/64
  stageA(0, 0); stageB(0, 0);
  asm volatile("s_waitcnt vmcnt(0)" ::: "memory");
  __builtin_amdgcn_s_barrier();
#pragma unroll
  for (int t = 0; t < NT; ++t) {
    int bf = t & 1;
    // phase 0 (kk=0)
    short8 a0[4], b0[4];
    dsA(bf, 0, a0); dsB(bf, 0, b0);
    if (t + 1 < NT) stageA(bf ^ 1, (t + 1) * 64);
    __builtin_amdgcn_s_barrier();
    LGKM0_FENCE();
    mf16(a0, b0);
    __builtin_amdgcn_s_barrier();
    // phase 1 (kk=1)
    short8 a1[4], b1[4];
    dsA(bf, 1, a1); dsB(bf, 1, b1);
    if (t + 1 < NT) stageB(bf ^ 1, (t + 1) * 64);
    __builtin_amdgcn_s_barrier();
    LGKM0_FENCE();
    mf16(a1, b1);
    if (t + 1 < NT) {
      asm volatile("s_waitcnt vmcnt(0)" ::: "memory");
      __builtin_amdgcn_s_barrier();
    }
  }

  // epilogue: bias + relu, bf16 store. C/D: row=(lane>>4)*4+q, col=lane&15
#pragma unroll
  for (int n = 0; n < 4; ++n) {
    int gcol = bcol + wc*64 + n*16 + lr;
    float bias = b1[gcol];
#pragma unroll
    for (int m = 0; m < 4; ++m) {
      int grow0 = brow + wr*64 + m*16 + lhi*4;
#pragma unroll
      for (int q = 0; q < 4; ++q) {
        float v = acc[m][n][q] + bias;
        v = v > 0.f ? v : 0.f;
        X1[(size_t)(grow0 + q) * D1_ + gcol] = f2bf(v);
      }
    }
  }
}

// ---------------------------------------------------------------- K3: GEMM2 + relu + max over j
// BM=192 (4 j-groups), BN=256, BK=64, 8 waves (2M x 4N), wave tile 96x64.
// A dbuf (1 ahead) + B tribuf (2 ahead), 144 KB. 4 phases per K-tile:
// ph = (m-triple) x (kk-half), each {ds_read; stage-slice; bar; lgkm0;
// setprio; 12 MFMA; setprio; bar}. One counted vmcnt(4) per K-tile.
__global__ __launch_bounds__(512, 2) void k_gemm2(const short* __restrict__ X1,
                                                  const short* __restrict__ W2b,
                                                  const float* __restrict__ b2,
                                                  float* __restrict__ out) {
  __shared__ short Abuf[2][192 * 64];   //  48 KB
  __shared__ short Bbuf[3][256 * 64];   //  96 KB  (total 144 KB)
  int tid = threadIdx.x;
  int wid = tid >> 6, lane = tid & 63;
  // T1: grid 1536 = 8 * 192
  int wgid = (blockIdx.x & 7) * 192 + (blockIdx.x >> 3);
  int tm = wgid >> 2, tn = wgid & 3;
  int brow = tm * 192, bcol = tn * 256;
  int wr = wid >> 2, wc = wid & 3;
  int lr = lane & 15, lhi = lane >> 4;
  int sx = lr & 7;

  f32x4 acc[6][4];
#pragma unroll
  for (int m = 0; m < 6; ++m)
#pragma unroll
    for (int n = 0; n < 4; ++n) acc[m][n] = (f32x4){0.f, 0.f, 0.f, 0.f};

  auto stageA = [&](int buf, int k0) {   // 1536 granules / 512 thr = 3
#pragma unroll
    for (int it = 0; it < 3; ++it) {
      int fg = it * 512 + tid;
      int r = fg >> 3, gs = (fg & 7) ^ (r & 7);
      async16(&X1[(size_t)(brow + r) * D1_ + k0 + (gs << 3)], &Abuf[buf][fg * 8]);
    }
  };
  auto stageBh = [&](int buf, int k0, int half) {  // 2 of 4 B-iters
#pragma unroll
    for (int it = 0; it < 2; ++it) {
      int fg = (half * 2 + it) * 512 + tid;
      int r = fg >> 3, gs = (fg & 7) ^ (r & 7);
      async16(&W2b[(size_t)(bcol + r) * D1_ + k0 + (gs << 3)], &Bbuf[buf][fg * 8]);
    }
  };
  auto dsA3 = [&](int buf, int kk, int mb, short8* a) {
    int gr = kk * 4 + lhi;
#pragma unroll
    for (int m = 0; m < 3; ++m)
      a[m] = *(const short8*)&Abuf[buf][(wr*96 + (mb + m)*16 + lr) * 64 + ((gr ^ sx) << 3)];
  };
  auto dsB4 = [&](int buf, int kk, short8* b) {
    int gr = kk * 4 + lhi;
#pragma unroll
    for (int n = 0; n < 4; ++n)
      b[n] = *(const short8*)&Bbuf[buf][(wc*64 + n*16 + lr) * 64 + ((gr ^ sx) << 3)];
  };
  auto mf12 = [&](short8* a, short8* b, int mb) {
    __builtin_amdgcn_s_setprio(1);
#pragma unroll
    for (int m = 0; m < 3; ++m)
#pragma unroll
      for (int n = 0; n < 4; ++n)
        acc[mb + m][n] = mfma16(a[m], b[n], acc[mb + m][n]);
    __builtin_amdgcn_s_setprio(0);
  };

  const int NT = 8;                      // D1_/64
  // prologue: A(0), B(0), B(1); wait A(0)+B(0) landed (B(1)'s 4 in flight)
  stageA(0, 0); stageBh(0, 0, 0); stageBh(0, 0, 1);
  stageBh(1, 64, 0); stageBh(1, 64, 1);
  asm volatile("s_waitcnt vmcnt(4)" ::: "memory");
  __builtin_amdgcn_s_barrier();
#pragma unroll
  for (int t = 0; t < NT; ++t) {
    int bA = t & 1, bB = t % 3;
    // ---- phase 0: (m0-2, kk0)
    short8 a0[3], b0[4];
    dsA3(bA, 0, 0, a0); dsB4(bB, 0, b0);
    if (t + 1 < NT) stageA(bA ^ 1, (t + 1) * 64);
    __builtin_amdgcn_s_barrier();
    LGKM0_FENCE();
    mf12(a0, b0, 0);
    __builtin_amdgcn_s_barrier();
    // ---- phase 1: (m3-5, kk0)
    short8 a1[3];
    dsA3(bA, 0, 3, a1);
    if (t + 2 < NT) stageBh((t + 2) % 3, (t + 2) * 64, 0);
    __builtin_amdgcn_s_barrier();
    LGKM0_FENCE();
    mf12(a1, b0, 3);
    __builtin_amdgcn_s_barrier();
    // ---- phase 2: (m0-2, kk1)
    short8 a2[3], b1[4];
    dsA3(bA, 1, 0, a2); dsB4(bB, 1, b1);
    if (t + 2 < NT) stageBh((t + 2) % 3, (t + 2) * 64, 1);
    __builtin_amdgcn_s_barrier();
    LGKM0_FENCE();
    mf12(a2, b1, 0);
    __builtin_amdgcn_s_barrier();
    // ---- phase 3: (m3-5, kk1)
    short8 a3[3];
    dsA3(bA, 1, 3, a3);
    __builtin_amdgcn_s_barrier();
    LGKM0_FENCE();
    mf12(a3, b1, 3);
    // end-of-tile: counted wait (A(t+1) landed; B(t+2) stays in flight)
    if (t + 2 < NT)      { asm volatile("s_waitcnt vmcnt(4)" ::: "memory"); }
    else if (t + 1 < NT) { asm volatile("s_waitcnt vmcnt(0)" ::: "memory"); }
    if (t + 1 < NT) __builtin_amdgcn_s_barrier();
  }

  // epilogue: wave rows = 2 j-groups (m 0..2 and 3..5); max + shfl reduce
  int gbase = tm * 4 + wr * 2;
#pragma unroll
  for (int n = 0; n < 4; ++n) {
    int gcol = bcol + wc*64 + n*16 + lr;
    float bias = b2[gcol];
    float r0 = 0.f, r1 = 0.f;            // relu floor == identity for max(relu)
#pragma unroll
    for (int m = 0; m < 3; ++m)
#pragma unroll
      for (int q = 0; q < 4; ++q) {
        float v0 = acc[m][n][q] + bias;
        float v1 = acc[m + 3][n][q] + bias;
        if (v0 > r0) r0 = v0;
        if (v1 > r1) r1 = v1;
      }
    r0 = fmaxf(r0, __shfl_xor(r0, 16));
    r0 = fmaxf(r0, __shfl_xor(r0, 32));
    r1 = fmaxf(r1, __shfl_xor(r1, 16));
    r1 = fmaxf(r1, __shfl_xor(r1, 32));
    if (lhi == 0) {
      out[(size_t)gbase       * D2_ + gcol] = r0;
      out[(size_t)(gbase + 1) * D2_ + gcol] = r1;
    }
  }
}

// ----------------------------------------------------------------
extern "C" void kernel_launch(void* const* d_in, const int* in_sizes, int n_in,
                              void* d_out, int out_size, void* d_ws, size_t ws_size,
                              hipStream_t stream) {
  const float* h_states = (const float*)d_in[0];
  const float* traj = (const float*)d_in[3];
  const float* tw   = (const float*)d_in[4];
  const float* Wse  = (const float*)d_in[6];
  const float* bse  = (const float*)d_in[7];
  const float* W1   = (const float*)d_in[8];
  const float* b1   = (const float*)d_in[9];
  const float* W2   = (const float*)d_in[10];
  const float* b2   = (const float*)d_in[11];
  float* out = (float*)d_out;

  char* ws = (char*)d_ws;
  const size_t X_BYTES   = (size_t)M_ * K1_ * 2;   // 84,934,656
  const size_t X1_BYTES  = (size_t)M_ * D1_ * 2;   // 75,497,472
  const size_t W1B_BYTES = (size_t)D1_ * K1_ * 2;  //    589,824
  short* X   = (short*)ws;
  short* X1  = (short*)(ws + X_BYTES);
  short* W1b = (short*)(ws + X_BYTES + X1_BYTES);
  short* W2b = (short*)(ws + X_BYTES + X1_BYTES + W1B_BYTES);
  // oW (3 MB fp32) aliases head of X1: consumed by k_build_x before k_gemm1
  float* oW  = (float*)(ws + X_BYTES);

  k_cvt_w  <<<(D1_*K1_ + D2_*D1_ + 255) / 256, 256, 0, stream>>>(W1, W2, W1b, W2b);
  k_oW     <<<B_ * 2, 256, 0, stream>>>(traj, Wse, oW);
  k_build_x<<<M_ / 4, 256, 0, stream>>>(tw, h_states, bse, oW, X);
  k_gemm1  <<<(M_ / 128) * (D1_ / 128), 256, 0, stream>>>(X, W1b, b1, X1);
  k_gemm2  <<<(M_ / 192) * (D2_ / 256), 512, 0, stream>>>(X1, W2b, b2, out);
}